// Round 4
// baseline (240.219 us; speedup 1.0000x reference)
//
#include <hip/hip_runtime.h>

using i32x4 = __attribute__((ext_vector_type(4))) int;

#define AS3(p) ((__attribute__((address_space(3))) void*)(p))
#define AS1(p) ((const __attribute__((address_space(1))) void*)(p))

constexpr int M = 8192;
constexpr int N = 4096;
constexpr int K = 4096;
constexpr int BK = 64;           // 64 B/row per K-tile
constexpr int NT = K / BK;       // 64 K-tiles
constexpr int NBUF = 4;          // 4-deep LDS ring -> prefetch 3 tiles ahead

// ---------------- Pass 1a: pack x (int32 -> int8), layout preserved [M][K] ----------------
__global__ void pack_a_kernel(const int4* __restrict__ x, unsigned* __restrict__ a8, int nUnits) {
    int stride = gridDim.x * blockDim.x;
    for (int u = blockIdx.x * blockDim.x + threadIdx.x; u < nUnits; u += stride) {
        int4 v = x[u];
        a8[u] = (v.x & 255) | ((v.y & 255) << 8) | ((v.z & 255) << 16) | (v.w << 24);
    }
}

// ---------------- Pass 1b: pack + transpose W: [K][N] int32 -> [N][K] int8 ----------------
__global__ void pack_wT_kernel(const int* __restrict__ w, char* __restrict__ b8t) {
    __shared__ __align__(16) char T[64][80];
    const int n0 = blockIdx.x * 64;
    const int k0 = blockIdx.y * 64;
    const int tid = threadIdx.x;

    #pragma unroll
    for (int i = 0; i < 4; i++) {
        int u = tid + i * 256;
        int r = u >> 4;
        int c = u & 15;
        int4 v = *(const int4*)&w[(size_t)(k0 + r) * N + n0 + 4 * c];
        T[4 * c + 0][r] = (char)v.x;
        T[4 * c + 1][r] = (char)v.y;
        T[4 * c + 2][r] = (char)v.z;
        T[4 * c + 3][r] = (char)v.w;
    }
    __syncthreads();

    const int n = tid >> 2;
    const int q = tid & 3;
    int4 val = *(const int4*)&T[n][16 * q];
    *(int4*)&b8t[(size_t)(n0 + n) * K + k0 + 16 * q] = val;
}

// ---------------- Pass 2: i8 GEMM, 256x256 tile, BK=64, 4-buffer ring, pipe-overlapped ----------------
// One barrier per K-tile (buffer rotation only). Fragment ds_reads are plain loads,
// software-pipelined one A-fragment ahead of each MFMA cluster; the compiler emits
// counted lgkmcnt so the LDS pipe services read m+1 while the matrix pipe runs MFMA m.
// Chunk swizzle (both sides): slot (row,c) holds global chunk c ^ ((row>>1)&3) ->
// residual 2-way bank aliasing = free (PMC-verified 0 conflicts in R2/R3).
// Steady state: 12 global_load_lds in flight; tile-end waits vmcnt(8) (counted, never 0).
__global__ __launch_bounds__(512, 2) void gemm_i8_kernel(
    const char* __restrict__ a8, const char* __restrict__ b8t,
    const int* __restrict__ bias, const float* __restrict__ scales,
    float* __restrict__ out)
{
    __shared__ __align__(16) char As[NBUF][256 * BK];   // 16 KB each
    __shared__ __align__(16) char Bs[NBUF][256 * BK];   // total 128 KB -> 1 block/CU

    const int tid  = threadIdx.x;
    const int lane = tid & 63;
    const int wid  = tid >> 6;
    const int wr   = wid >> 2;   // 0..1 -> 128-row band
    const int wc   = wid & 3;    // 0..3 -> 64-col band

    // XCD-aware remap: each XCD covers an 8x8 (tm,tn) square (FETCH 148->98 MB in R3)
    const int bid = blockIdx.x;
    const int xcd = bid & 7;
    const int l   = bid >> 3;
    const int tm  = (xcd >> 1) * 8 + (l >> 3);   // 0..31
    const int tn  = (xcd & 1) * 8 + (l & 7);     // 0..15
    const size_t brow = (size_t)tm * 256;
    const size_t bcol = (size_t)tn * 256;

    // Staging: 4 loads/thread/tile. Thread t -> row t>>2 (0..127), source chunk
    // (t&3) ^ ((row>>1)&3)  [pre-swizzled so linear LDS dest + swizzled read match].
    const int srow = tid >> 2;
    const int schS = ((tid & 3) ^ ((tid >> 3) & 3)) << 4;
    const char* aG = a8  + (brow + srow) * (size_t)K + schS;
    const char* bG = b8t + (bcol + srow) * (size_t)K + schS;
    const int ldsW = wid * 1024;   // wave-uniform dest; HW adds lane*16

    i32x4 acc[8][4];
    #pragma unroll
    for (int m = 0; m < 8; m++)
        #pragma unroll
        for (int n = 0; n < 4; n++)
            #pragma unroll
            for (int r = 0; r < 4; r++)
                acc[m][n][r] = 0;

    auto stage = [&](int slot, int kt) {
        const char* a = aG + (size_t)kt * BK;
        const char* b = bG + (size_t)kt * BK;
        char* Ad = &As[slot][0] + ldsW;
        char* Bd = &Bs[slot][0] + ldsW;
        __builtin_amdgcn_global_load_lds(AS1(a),                  AS3(Ad),        16, 0, 0);
        __builtin_amdgcn_global_load_lds(AS1(a + (size_t)128*K),  AS3(Ad + 8192), 16, 0, 0);
        __builtin_amdgcn_global_load_lds(AS1(b),                  AS3(Bd),        16, 0, 0);
        __builtin_amdgcn_global_load_lds(AS1(b + (size_t)128*K),  AS3(Bd + 8192), 16, 0, 0);
    };

    // Fragment read: row = band + m*16 + (lane&15); chunk c = lane>>4, swizzled by
    // ((row>>1)&3) = (((lane&15)>>1)&3) since band/m offsets are multiples of 16.
    const int frow  = lane & 15;
    const int c0sw  = ((lane >> 4) ^ ((frow >> 1) & 3)) << 4;
    const int raOff = wr * 8192 + frow * 64 + c0sw;
    const int rbOff = wc * 4096 + frow * 64 + c0sw;

    // Prologue: fill 3 buffers, wait only the first.
    stage(0, 0);
    stage(1, 1);
    stage(2, 2);
    asm volatile("s_waitcnt vmcnt(8)" ::: "memory");
    __builtin_amdgcn_s_barrier();

    for (int t = 0; t < NT; ++t) {
        const int slot = t & 3;
        if (t + 3 < NT) stage((t + 3) & 3, t + 3);

        const char* Ab = &As[slot][0] + raOff;
        const char* Bb = &Bs[slot][0] + rbOff;

        i32x4 bfr[4];
        #pragma unroll
        for (int n = 0; n < 4; ++n)
            bfr[n] = *(const i32x4*)(Bb + n * 1024);

        i32x4 aCur = *(const i32x4*)(Ab);
        __builtin_amdgcn_s_setprio(1);
        #pragma unroll
        for (int m = 0; m < 8; ++m) {
            i32x4 aNext;
            if (m < 7) aNext = *(const i32x4*)(Ab + (m + 1) * 1024);
            #pragma unroll
            for (int n = 0; n < 4; ++n)
                acc[m][n] = __builtin_amdgcn_mfma_i32_16x16x64_i8(aCur, bfr[n], acc[m][n], 0, 0, 0);
            aCur = aNext;
        }
        __builtin_amdgcn_s_setprio(0);

        // counted drain: 12 stages outstanding in steady state; wait oldest 4 -> slot t+1 ready.
        // asm memory clobber = compiler fence both directions (protects next tile's ds_reads).
        if (t <= NT - 4) asm volatile("s_waitcnt vmcnt(8)" ::: "memory");
        else             asm volatile("s_waitcnt vmcnt(0)" ::: "memory");
        __builtin_amdgcn_s_barrier();
    }

    // epilogue: D col = lane&15 (N-dim), row = (lane>>4)*4 + reg (absmax 0 in r1-r3)
    #pragma unroll
    for (int n = 0; n < 4; ++n) {
        const int col = (int)bcol + wc * 64 + n * 16 + (lane & 15);
        const int bv  = bias[col];
        const float sv = scales[col];
        #pragma unroll
        for (int m = 0; m < 8; ++m) {
            const size_t row0 = brow + wr * 128 + m * 16 + ((lane >> 4) << 2);
            float* o = out + row0 * (size_t)N + col;
            #pragma unroll
            for (int r = 0; r < 4; ++r)
                o[(size_t)r * N] = (float)(acc[m][n][r] + bv) * sv;
        }
    }
}

extern "C" void kernel_launch(void* const* d_in, const int* in_sizes, int n_in,
                              void* d_out, int out_size, void* d_ws, size_t ws_size,
                              hipStream_t stream) {
    const int*   x      = (const int*)d_in[0];
    const int*   w      = (const int*)d_in[1];
    const int*   bias   = (const int*)d_in[2];
    const float* scales = (const float*)d_in[3];
    float* out = (float*)d_out;

    char* a8  = (char*)d_ws;                       // M*K = 32 MB
    char* b8t = a8 + (size_t)M * K;                // N*K = 16 MB

    pack_a_kernel<<<2048, 256, 0, stream>>>((const int4*)x, (unsigned*)a8, M * K / 4);

    dim3 gt(N / 64, K / 64);
    pack_wT_kernel<<<gt, 256, 0, stream>>>(w, b8t);

    gemm_i8_kernel<<<(M / 256) * (N / 256), 512, 0, stream>>>(a8, b8t, bias, scales, out);
}

// Round 5
// 229.841 us; speedup vs baseline: 1.0452x; 1.0452x over previous
//
#include <hip/hip_runtime.h>

using i32x4 = __attribute__((ext_vector_type(4))) int;

#define AS3(p) ((__attribute__((address_space(3))) void*)(p))
#define AS1(p) ((const __attribute__((address_space(1))) void*)(p))

constexpr int M = 8192;
constexpr int N = 4096;
constexpr int K = 4096;
constexpr int BK = 64;           // 64 B/row per K-tile
constexpr int NT = K / BK;       // 64 K-tiles
constexpr int NBUF = 4;          // 4-deep LDS ring

// ---------------- Pass 1a: pack x (int32 -> int8), layout preserved [M][K] ----------------
__global__ void pack_a_kernel(const int4* __restrict__ x, unsigned* __restrict__ a8, int nUnits) {
    int stride = gridDim.x * blockDim.x;
    for (int u = blockIdx.x * blockDim.x + threadIdx.x; u < nUnits; u += stride) {
        int4 v = x[u];
        a8[u] = (v.x & 255) | ((v.y & 255) << 8) | ((v.z & 255) << 16) | (v.w << 24);
    }
}

// ---------------- Pass 1b: pack + transpose W: [K][N] int32 -> [N][K] int8 ----------------
__global__ void pack_wT_kernel(const int* __restrict__ w, char* __restrict__ b8t) {
    __shared__ __align__(16) char T[64][80];
    const int n0 = blockIdx.x * 64;
    const int k0 = blockIdx.y * 64;
    const int tid = threadIdx.x;

    #pragma unroll
    for (int i = 0; i < 4; i++) {
        int u = tid + i * 256;
        int r = u >> 4;
        int c = u & 15;
        int4 v = *(const int4*)&w[(size_t)(k0 + r) * N + n0 + 4 * c];
        T[4 * c + 0][r] = (char)v.x;
        T[4 * c + 1][r] = (char)v.y;
        T[4 * c + 2][r] = (char)v.z;
        T[4 * c + 3][r] = (char)v.w;
    }
    __syncthreads();

    const int n = tid >> 2;
    const int q = tid & 3;
    int4 val = *(const int4*)&T[n][16 * q];
    *(int4*)&b8t[(size_t)(n0 + n) * K + k0 + 16 * q] = val;
}

// ---------------- Pass 2: i8 GEMM, 256x256 tile, BK=64, register-double-buffered fragments ----------------
// Lockstep skeleton (R3, proven): 1 barrier + counted vmcnt per tile. New: MFMAs consume
// fragments read during the PREVIOUS tile (in registers); this tile's 12 ds_read_b128
// (for tile t+1) are issued first and complete under the MFMA cluster -> LDS pipe and
// matrix pipe overlap. lgkmcnt(0) at body end (free) makes slot-reuse WAR airtight.
// Chunk swizzle both-sides as R2/R3 (PMC: 0 conflicts).
__global__ __launch_bounds__(512, 2) void gemm_i8_kernel(
    const char* __restrict__ a8, const char* __restrict__ b8t,
    const int* __restrict__ bias, const float* __restrict__ scales,
    float* __restrict__ out)
{
    __shared__ __align__(16) char As[NBUF][256 * BK];   // 16 KB each
    __shared__ __align__(16) char Bs[NBUF][256 * BK];   // total 128 KB -> 1 block/CU

    const int tid  = threadIdx.x;
    const int lane = tid & 63;
    const int wid  = tid >> 6;
    const int wr   = wid >> 2;   // 0..1 -> 128-row band
    const int wc   = wid & 3;    // 0..3 -> 64-col band

    // XCD-aware remap: each XCD covers an 8x8 (tm,tn) square (FETCH 148->98 MB in R3)
    const int bid = blockIdx.x;
    const int xcd = bid & 7;
    const int l   = bid >> 3;
    const int tm  = (xcd >> 1) * 8 + (l >> 3);   // 0..31
    const int tn  = (xcd & 1) * 8 + (l & 7);     // 0..15
    const size_t brow = (size_t)tm * 256;
    const size_t bcol = (size_t)tn * 256;

    // Staging: 4 loads/thread/tile. Thread t -> row t>>2 (0..127), source chunk
    // (t&3) ^ ((row>>1)&3)  [pre-swizzled so linear LDS dest + swizzled read match].
    const int srow = tid >> 2;
    const int schS = ((tid & 3) ^ ((tid >> 3) & 3)) << 4;
    const char* aG = a8  + (brow + srow) * (size_t)K + schS;
    const char* bG = b8t + (bcol + srow) * (size_t)K + schS;
    const int ldsW = wid * 1024;   // wave-uniform dest; HW adds lane*16

    i32x4 acc[8][4];
    #pragma unroll
    for (int m = 0; m < 8; m++)
        #pragma unroll
        for (int n = 0; n < 4; n++)
            #pragma unroll
            for (int r = 0; r < 4; r++)
                acc[m][n][r] = 0;

    auto stage = [&](int slot, int kt) {
        const char* a = aG + (size_t)kt * BK;
        const char* b = bG + (size_t)kt * BK;
        char* Ad = &As[slot][0] + ldsW;
        char* Bd = &Bs[slot][0] + ldsW;
        __builtin_amdgcn_global_load_lds(AS1(a),                  AS3(Ad),        16, 0, 0);
        __builtin_amdgcn_global_load_lds(AS1(a + (size_t)128*K),  AS3(Ad + 8192), 16, 0, 0);
        __builtin_amdgcn_global_load_lds(AS1(b),                  AS3(Bd),        16, 0, 0);
        __builtin_amdgcn_global_load_lds(AS1(b + (size_t)128*K),  AS3(Bd + 8192), 16, 0, 0);
    };

    // Fragment read: row = band + m*16 + (lane&15); chunk c = lane>>4, swizzled by
    // ((row>>1)&3) = (((lane&15)>>1)&3) since band/m offsets are multiples of 16.
    const int frow  = lane & 15;
    const int c0sw  = ((lane >> 4) ^ ((frow >> 1) & 3)) << 4;
    const int raOff = wr * 8192 + frow * 64 + c0sw;
    const int rbOff = wc * 4096 + frow * 64 + c0sw;

    // Two named fragment sets (static indexing only — rule #20).
    i32x4 fAa[8], fAb[4], fBa[8], fBb[4];

    // ---- Prologue: fill all 4 slots; read tile-0 fragments; align. ----
    stage(0, 0); stage(1, 1); stage(2, 2); stage(3, 3);
    asm volatile("s_waitcnt vmcnt(8)" ::: "memory");   // stages 0,1 complete (mine)
    __builtin_amdgcn_s_barrier();                      // -> slots 0,1 readable by all
    {
        const char* Ab = &As[0][0] + raOff;
        const char* Bb = &Bs[0][0] + rbOff;
        #pragma unroll
        for (int n = 0; n < 4; ++n) fAb[n] = *(const i32x4*)(Bb + n * 1024);
        #pragma unroll
        for (int m = 0; m < 8; ++m) fAa[m] = *(const i32x4*)(Ab + m * 1024);
    }
    asm volatile("s_waitcnt lgkmcnt(0)" ::: "memory"); // my slot-0 reads done
    __builtin_amdgcn_s_barrier();                      // everyone's done -> slot 0 reusable

    auto body = [&](int t, i32x4 (&cA)[8], i32x4 (&cB)[4], i32x4 (&nA)[8], i32x4 (&nB)[4]) {
        if (t + 4 < NT) stage(t & 3, t + 4);           // slot t%4 is dead (cA already in regs)
        if (t + 1 < NT) {
            const int slot = (t + 1) & 3;
            const char* Ab = &As[slot][0] + raOff;
            const char* Bb = &Bs[slot][0] + rbOff;
            #pragma unroll
            for (int n = 0; n < 4; ++n) nB[n] = *(const i32x4*)(Bb + n * 1024);
            #pragma unroll
            for (int m = 0; m < 8; ++m) nA[m] = *(const i32x4*)(Ab + m * 1024);
        }
        __builtin_amdgcn_sched_barrier(0);             // pin stage+reads ABOVE the MFMA cluster
        __builtin_amdgcn_s_setprio(1);
        #pragma unroll
        for (int m = 0; m < 8; ++m)
            #pragma unroll
            for (int n = 0; n < 4; ++n)
                acc[m][n] = __builtin_amdgcn_mfma_i32_16x16x64_i8(cA[m], cB[n], acc[m][n], 0, 0, 0);
        __builtin_amdgcn_s_setprio(0);
        // my next-tile reads done (issued ~1300 cyc ago -> free); required before others
        // may overwrite slot t+1's ring predecessor
        asm volatile("s_waitcnt lgkmcnt(0)" ::: "memory");
        // counted drain: ensure MY stage(t+2) landed, then barrier -> slot t+2 readable by all
        if (t < NT - 4)       asm volatile("s_waitcnt vmcnt(8)" ::: "memory");
        else if (t == NT - 4) asm volatile("s_waitcnt vmcnt(4)" ::: "memory");
        else                  asm volatile("s_waitcnt vmcnt(0)" ::: "memory");
        __builtin_amdgcn_s_barrier();
    };

    for (int t = 0; t < NT; t += 2) {                  // NT even: static double-buffer swap
        body(t,     fAa, fAb, fBa, fBb);
        body(t + 1, fBa, fBb, fAa, fAb);
    }

    // epilogue: D col = lane&15 (N-dim), row = (lane>>4)*4 + reg (absmax 0 in r1-r4)
    #pragma unroll
    for (int n = 0; n < 4; ++n) {
        const int col = (int)bcol + wc * 64 + n * 16 + (lane & 15);
        const int bv  = bias[col];
        const float sv = scales[col];
        #pragma unroll
        for (int m = 0; m < 8; ++m) {
            const size_t row0 = brow + wr * 128 + m * 16 + ((lane >> 4) << 2);
            float* o = out + row0 * (size_t)N + col;
            #pragma unroll
            for (int r = 0; r < 4; ++r)
                o[(size_t)r * N] = (float)(acc[m][n][r] + bv) * sv;
        }
    }
}

extern "C" void kernel_launch(void* const* d_in, const int* in_sizes, int n_in,
                              void* d_out, int out_size, void* d_ws, size_t ws_size,
                              hipStream_t stream) {
    const int*   x      = (const int*)d_in[0];
    const int*   w      = (const int*)d_in[1];
    const int*   bias   = (const int*)d_in[2];
    const float* scales = (const float*)d_in[3];
    float* out = (float*)d_out;

    char* a8  = (char*)d_ws;                       // M*K = 32 MB
    char* b8t = a8 + (size_t)M * K;                // N*K = 16 MB

    pack_a_kernel<<<2048, 256, 0, stream>>>((const int4*)x, (unsigned*)a8, M * K / 4);

    dim3 gt(N / 64, K / 64);
    pack_wT_kernel<<<gt, 256, 0, stream>>>(w, b8t);

    gemm_i8_kernel<<<(M / 256) * (N / 256), 512, 0, stream>>>(a8, b8t, bias, scales, out);
}